// Round 12
// baseline (236.327 us; speedup 1.0000x reference)
//
#include <hip/hip_runtime.h>
#include <cstdint>

#define GH 10
#define GW 10

// Round 17: r11 + ILP chain-splitting. r11 (pair-split fill) TIED r2 to
// 0.03% -> fill wasn't binding. Diagnosis from counters: VALUBusy ~30% =
// ~3 waves/SIMD x ~25% issue duty, where 25% comes from the four ~50-deep
// SERIAL fma chains per lane (sc 55-deep, S_T 50, sum/box ~50; dependent
// fma ~4cyc). Fix = ILP, not more TLP: split every accumulator into
// independent sub-chains: even/odd ROWS at the outer level (2 chains per
// quantity) and even/odd COLUMNS inside each row (5-deep, not 10).
// Also: block reduction -> per-wave shfl tree + 1 atomic/wave (no LDS, no
// __syncthreads, cleaner tail). Loads/fill/argmin/epilogue = r11 verbatim.
// NOTE: this reorders FP sums. Tolerance evidence: cross-block atomicAdd
// order is already nondeterministic yet absmax reported 0.0 for 10 rounds
// -> comparison is not bit-exact. If this round fails absmax, revert here.
__global__ __launch_bounds__(256, 4) void custom_loss_kernel(
    const float* __restrict__ result,
    const int* __restrict__ points,
    float* __restrict__ out,
    int B)
{
    const int tix = threadIdx.x;
    const int lane = tix & 63;

    const int s_local = tix >> 1;             // sample within block (0..127)
    const int h = tix & 1;                    // half: rows 5h..5h+4
    const int s = blockIdx.x * 128 + s_local;

    float loss = 0.f;
    if (s < B) {
        const int4 p = ((const int4*)points)[s];
        const int p0y = p.x, p0x = p.y, p1y = p.z, p1x = p.w;
        const int dy0 = abs(p0y - p1y), dx0 = abs(p0x - p1x);
        const int base0 = dy0 + dx0;
        const int idx0 = p0y * GW + p0x;
        const int idx1 = p1y * GW + p1x;

        // ---- own 5 rows (50 floats) straight from global into registers ----
        const float* __restrict__ sp = result + (size_t)s * 100;
        const float2* __restrict__ rp2 = (const float2*)(sp + h * 50);
        float vv[50];
#pragma unroll
        for (int i = 0; i < 25; ++i) {
            const float2 t = rp2[i];
            vv[2 * i] = t.x; vv[2 * i + 1] = t.y;
        }
        const float rs = sp[idx0];            // L1-hot: lines just fetched
        const float re = sp[idx1];

        float adxf[10], inboxf[10];           // compile-time indexed -> regs
#pragma unroll
        for (int x = 0; x < 10; ++x) {
            const int a = abs(x - p0x) + abs(x - p1x) - dx0;
            adxf[x] = (float)a;
            inboxf[x] = (a == 0) ? 1.f : 0.f;
        }

        // ---- pass 1: split accumulator chains (even/odd rows & columns) ----
        float sumA = 0.f, sumB = 0.f;         // row-split sum
        float scA = 0.f, scB = 0.f;           // row-split sc
        float boxA = 0.f, boxB = 0.f;         // row-split box
        uint64_t mword = 0;                   // own 50-bit mask, bit = i*10+x
#pragma unroll
        for (int i = 0; i < 5; ++i) {
            const int y = 5 * h + i;
            const float* v = vv + 10 * i;
            const float rowacc = ((v[0]+v[1])+(v[2]+v[3])) +
                                 ((v[4]+v[5])+(v[6]+v[7])) + (v[8]+v[9]);
            const int ay = abs(y - p0y) + abs(y - p1y) - dy0;
            // column-split 5-deep chains within the row
            float rscE = 0.f, rscO = 0.f, rbxE = 0.f, rbxO = 0.f;
            uint32_t rm = 0u;
#pragma unroll
            for (int x = 0; x < 10; x += 2) {
                rscE = fmaf(adxf[x],     v[x],     rscE);
                rscO = fmaf(adxf[x + 1], v[x + 1], rscO);
                rbxE = fmaf(inboxf[x],     v[x],     rbxE);
                rbxO = fmaf(inboxf[x + 1], v[x + 1], rbxO);
                // jnp.round half-to-even: for v in [0,1), round==1 <=> v>0.5
                rm |= (v[x]     > 0.5f) ? (1u << x)       : 0u;
                rm |= (v[x + 1] > 0.5f) ? (1u << (x + 1)) : 0u;
            }
            const float rsc = fmaf((float)ay, rowacc, rscE + rscO);
            const float rbx = (ay == 0) ? (rbxE + rbxO) : 0.f;
            if (i & 1) { sumB += rowacc; scB += rsc; boxB += rbx; }
            else       { sumA += rowacc; scA += rsc; boxA += rbx; }
            mword |= (uint64_t)rm << (10 * i);
        }
        const float sum_h = sumA + sumB;
        const float sc_h  = scA + scB;
        const float box_h = boxA + boxB;
        const float sum_all = sum_h + __shfl_xor(sum_h, 1);
        const float sc      = sc_h  + __shfl_xor(sc_h, 1);
        const float boxSum  = box_h + __shfl_xor(box_h, 1);

        // ---- flood fill: pair-split, one 50-bit word per lane (r11) ----
        const uint64_t M50 = (1ull << 50) - 1;
        const uint64_t C0  = 0x10040100401ull;        // col-0 bit of 5 rows
        const uint64_t NC0 = M50 & ~C0;
        const uint64_t NC9 = M50 & ~(C0 << 9);
        const uint64_t msk = mword;
        uint64_t c = 0;
        if (h == 0) { if (idx0 < 50)  c = 1ull << idx0; }
        else        { if (idx0 >= 50) c = 1ull << (idx0 - 50); }
#pragma unroll 1
        for (int it = 0; it < GH + GW; ++it) {        // cap 20 = reference
            const uint64_t hx = c | ((c << 1) & NC0) | ((c >> 1) & NC9);
            const uint64_t hp = (uint64_t)__shfl_xor((unsigned long long)hx, 1);
            const uint64_t cross = h ? (hp >> 40) : (hp << 40);
            uint64_t n = (hx | (hx << 10) | (hx >> 10) | cross) & msk;
            n |= c;
            const int same = (n == c) ? 1 : 0;
            c = n;
            if (__all(same)) break;           // fixpoint absorbing: converged
        }
        const uint64_t cOth = (uint64_t)__shfl_xor((unsigned long long)c, 1);
        const uint64_t clo = h ? cOth : c;
        const uint64_t chi = h ? c : cOth;
        const int K = __popcll(clo) + __popcll(chi);

        // ---- S_T over own cells: split chains (rows A/B, columns E/O) ----
        // in_cl[y][x] = cluster bit (x*10+y); y = 5h+i -> pre-shift by 5h
        const uint64_t wlo = clo >> (5 * h);
        const uint64_t whi = chi >> (5 * h);
        float stA = 0.f, stB = 0.f;
#pragma unroll
        for (int i = 0; i < 5; ++i) {
            const float* v = vv + 10 * i;
            float rstE = 0.f, rstO = 0.f;
#pragma unroll
            for (int x = 0; x < 10; x += 2) {
                const uint64_t wE = (x < 5) ? wlo : whi;       // compile-time
                const uint64_t wO = ((x + 1) < 5) ? wlo : whi; // selects
                const uint32_t bE = (uint32_t)((wE >> ((x % 5) * 10 + i)) & 1ull);
                const uint32_t bO = (uint32_t)((wO >> (((x + 1) % 5) * 10 + i)) & 1ull);
                rstE = fmaf((float)bE, v[x],     rstE);
                rstO = fmaf((float)bO, v[x + 1], rstO);
            }
            if (i & 1) stB += rstE + rstO;
            else       stA += rstE + rstO;
        }
        const float st_h = stA + stB;
        const float S_T = st_h + __shfl_xor(st_h, 1);

        // ---- argmin (own 5 rows, then pair merge; first-flat-index ties) ----
        int bestd = 1000, bidx = 0;
        const uint64_t cw = h ? chi : clo;    // == own word c
#pragma unroll
        for (int i = 0; i < 5; ++i) {
            const int y = 5 * h + i;
            const uint32_t rb = (uint32_t)((cw >> (10 * i)) & 0x3FFull);
            const uint32_t left  = rb & ((2u << p1x) - 1);
            const uint32_t right = rb >> p1x;
            const int dl = left  ? (p1x - (31 - __builtin_clz(left))) : 1000;
            const int dr = right ? __builtin_ctz(right) : 1000;
            int dx, xx;
            if (dl <= dr) { dx = dl; xx = p1x - dl; }      // tie -> smaller col
            else          { dx = dr; xx = p1x + dr; }
            const int d = abs(y - p1y) + dx;
            if (rb && d < bestd) { bestd = d; bidx = y * GW + xx; }
        }
        {   // pair merge; tie -> smaller flat index
            const int od = __shfl_xor(bestd, 1);
            const int oi = __shfl_xor(bidx, 1);
            if (od < bestd || (od == bestd && oi < bidx)) { bestd = od; bidx = oi; }
        }

        // ---- epilogue (replicated; only h==0 contributes) ----
        const bool better = bestd < base0;
        const int ny = better ? bidx / 10 : p0y;
        const int nx = better ? bidx % 10 : p0x;
        const int gap = min(base0, bestd);

        int by = ny, bx = nx, bg = gap;
        const int oy = p1y - ny, ox = p1x - nx;
        auto upd = [&](bool cond, int cy, int cx) {
            const int d = abs(cy - p1y) + abs(cx - p1x);
            if (cond && (d < bg)) { by = cy; bx = cx; bg = d; }
        };
        upd(ox < 0,                     ny,     nx - 1);
        upd((ox < 0) && (ny != 0),      ny - 1, nx - 1);
        upd((ox < 0) && (ny != GH - 1), ny + 1, nx - 1);
        upd(ox > 0,                     ny,     nx + 1);
        upd((ox > 0) && (ny != 0),      ny - 1, nx + 1);
        upd((ox > 0) && (ny != GH - 1), ny + 1, nx + 1);
        upd(oy < 0,                     ny - 1, nx);
        upd(oy > 0,                     ny + 1, nx);
        const int ncy = min(max(by, 0), GH - 1);
        const int ncx = min(max(bx, 0), GW - 1);
        const float rn = sp[ncy * GW + ncx];  // L1/L2-hot gather

        const float csf = (float)K;
        const float nboxf = (float)((dy0 + 1) * (dx0 + 1));
        const float loss_start = (2.f - (rs + re)) * 1000.f;
        const float lon = 5.f * csf + 15.f * sum_all - 20.f * S_T;
        const float single_cell = 0.5f * sc + 20.f * (nboxf - boxSum);
        const float cpen = 12.f * csf * S_T;
        const float gap_pen = (float)gap * 300.f * (1.f - rn);
        loss = loss_start + lon + single_cell + cpen + gap_pen;
        if (h != 0) loss = 0.f;                   // one contribution per sample
    }

    // ---- reduction: per-wave shfl tree -> one atomic per wave (no LDS) ----
#pragma unroll
    for (int off = 32; off > 0; off >>= 1)
        loss += __shfl_down(loss, off);
    if (lane == 0) atomicAdd(out, loss);

}

extern "C" void kernel_launch(void* const* d_in, const int* in_sizes, int n_in,
                              void* d_out, int out_size, void* d_ws, size_t ws_size,
                              hipStream_t stream)
{
    const float* result = (const float*)d_in[0];
    const int* points   = (const int*)d_in[1];
    float* out = (float*)d_out;
    const int B = in_sizes[0] / 100;
    hipMemsetAsync(out, 0, sizeof(float), stream);   // harness poisons d_out
    const int block = 256;                            // 128 samples per block
    const int grid = (2 * B + block - 1) / block;
    custom_loss_kernel<<<grid, block, 0, stream>>>(result, points, out, B);
}